// Round 1
// baseline (753.863 us; speedup 1.0000x reference)
//
#include <hip/hip_runtime.h>
#include <hip/hip_bf16.h>

#define BATCH 8
#define CH 256
#define SPAT 16384
#define TP 64       // pixel tile
#define PITCH 260   // LDS channel pitch (520B rows: 8B-aligned, 4-way b16 write conflict only)

typedef __attribute__((ext_vector_type(4))) float f32x4;
typedef __attribute__((ext_vector_type(8))) __bf16 bf16x8;
typedef __attribute__((ext_vector_type(4))) __bf16 bf16x4;

// workspace float offsets
#define WS_SCALE   0        // 256
#define WS_SHIFT   256      // 256
#define WS_ROWSUM  512      // 2048  (zeroed)
#define WS_POOLED  2560     // 16
#define WS_CTX     4096     // 16*128*128 = 262144 (zeroed)
#define WS_MBF     266240   // 8*256*256 bf16 = 262144 floats
#define WS_WKBF    528384   // 65536 bf16 = 32768 floats
#define WS_WQBF    561152
#define WS_WVBF    593920
// total 626688 floats = 2.39 MB

__device__ __forceinline__ void blockReduce2(float& a, float& b, volatile float* sm) {
    int lane = threadIdx.x & 63, w = threadIdx.x >> 6;
#pragma unroll
    for (int o = 32; o; o >>= 1) { a += __shfl_down(a, o); b += __shfl_down(b, o); }
    if (lane == 0) { sm[w] = a; sm[4 + w] = b; }
    __syncthreads();
    if (threadIdx.x == 0) {
        a = sm[0] + sm[1] + sm[2] + sm[3];
        b = sm[4] + sm[5] + sm[6] + sm[7];
    }
}

// ---- convert projection weights fp32 -> bf16 ----
__global__ void ea_prep(const float* wk, const float* wq, const float* wv,
                        __bf16* wkb, __bf16* wqb, __bf16* wvb) {
    int i = blockIdx.x * 256 + threadIdx.x;   // 65536 threads, 1 elem per matrix
    wkb[i] = (__bf16)wk[i];
    wqb[i] = (__bf16)wq[i];
    wvb[i] = (__bf16)wv[i];
}

// ---- BN batch stats -> per-channel scale/shift ----
__global__ void ea_bnstats(const float* x, const float* gamma, const float* beta,
                           float* scale, float* shift) {
    __shared__ float sm[8];
    int c = blockIdx.x;
    float sum = 0.f, ss = 0.f;
    for (int b = 0; b < BATCH; b++) {
        const float4* p = (const float4*)(x + (size_t)(b * CH + c) * SPAT);
        for (int i = threadIdx.x; i < SPAT / 4; i += 256) {
            float4 v = p[i];
            sum += v.x + v.y + v.z + v.w;
            ss  += v.x * v.x + v.y * v.y + v.z * v.z + v.w * v.w;
        }
    }
    blockReduce2(sum, ss, sm);
    if (threadIdx.x == 0) {
        const float inv = 1.f / (float)(BATCH * SPAT);
        float mean = sum * inv;
        float var  = ss * inv - mean * mean;
        float rs   = rsqrtf(var + 1e-5f);
        float sc   = gamma[c] * rs;
        scale[c] = sc;
        shift[c] = beta[c] - mean * sc;
    }
}

// stage normalized x tile into LDS as [px][ch] bf16
__device__ __forceinline__ void stage_xn(const float* xb_base, const float* scale,
                                         const float* shift, __bf16* Xl, int t) {
    int px = t & 63, crow = t >> 6;
    const float* xb = xb_base + px;
#pragma unroll 4
    for (int i = 0; i < 64; i++) {
        int c = crow * 64 + i;                       // wave-uniform channel
        float v = xb[(size_t)c * SPAT];
        Xl[px * PITCH + c] = (__bf16)(v * scale[c] + shift[c]);
    }
}

// per-wave 64x64 strip of a [256 x 64px] GEMM, K=256. A global bf16 (row stride 256), B in LDS [px][ch].
__device__ __forceinline__ void mm256(const __bf16* __restrict__ A, const __bf16* Xl,
                                      int WB, int quad, int l15, f32x4 (&acc)[4][4]) {
#pragma unroll 2
    for (int ks = 0; ks < 8; ks++) {
        int k0 = ks * 32;
        bf16x8 a[4];
#pragma unroll
        for (int mt = 0; mt < 4; mt++)
            a[mt] = *(const bf16x8*)(A + (WB + mt * 16 + l15) * 256 + k0 + quad * 8);
        bf16x8 bb[4];
#pragma unroll
        for (int nt = 0; nt < 4; nt++) {
            const __bf16* p = Xl + (nt * 16 + l15) * PITCH + k0 + quad * 8;
            bf16x4 lo = *(const bf16x4*)p;
            bf16x4 hi = *(const bf16x4*)(p + 4);
            bb[nt] = __builtin_shufflevector(lo, hi, 0, 1, 2, 3, 4, 5, 6, 7);
        }
#pragma unroll
        for (int mt = 0; mt < 4; mt++)
#pragma unroll
            for (int nt = 0; nt < 4; nt++)
                acc[mt][nt] = __builtin_amdgcn_mfma_f32_16x16x32_bf16(a[mt], bb[nt], acc[mt][nt], 0, 0, 0);
    }
}

// ---- fused: normalize + K/V projection; writes p=exp(k+bk) and v as bf16; row sums of p ----
__global__ __launch_bounds__(256) void ea_projkv(const float* x, const float* scale, const float* shift,
                                                 const __bf16* wkb, const __bf16* wvb,
                                                 const float* bk, const float* bv,
                                                 __bf16* pbuf, __bf16* vbuf, float* rowsum) {
    __shared__ __bf16 X[TP * PITCH];
    int bi = blockIdx.x, b = bi >> 8, s0 = (bi & 255) * TP, t = threadIdx.x;
    stage_xn(x + (size_t)b * CH * SPAT + s0, scale, shift, X, t);
    __syncthreads();

    int lane = t & 63, wave = t >> 6, quad = lane >> 4, l15 = lane & 15, WB = wave * 64;
    const f32x4 z = {0.f, 0.f, 0.f, 0.f};

    // K projection -> p = exp(k)
    {
        f32x4 acc[4][4];
#pragma unroll
        for (int mt = 0; mt < 4; mt++)
#pragma unroll
            for (int nt = 0; nt < 4; nt++) acc[mt][nt] = z;
        mm256(wkb, X, WB, quad, l15, acc);
#pragma unroll
        for (int mt = 0; mt < 4; mt++) {
#pragma unroll
            for (int r = 0; r < 4; r++) {
                int row = WB + mt * 16 + quad * 4 + r;
                float bs = bk[row], rs = 0.f;
#pragma unroll
                for (int nt = 0; nt < 4; nt++) {
                    float p = __expf(acc[mt][nt][r] + bs);
                    rs += p;
                    pbuf[(size_t)(b * CH + row) * SPAT + s0 + nt * 16 + l15] = (__bf16)p;
                }
#pragma unroll
                for (int o = 1; o < 16; o <<= 1) rs += __shfl_xor(rs, o);
                if (l15 == 0) atomicAdd(rowsum + b * CH + row, rs);
            }
        }
    }
    // V projection
    {
        f32x4 acc[4][4];
#pragma unroll
        for (int mt = 0; mt < 4; mt++)
#pragma unroll
            for (int nt = 0; nt < 4; nt++) acc[mt][nt] = z;
        mm256(wvb, X, WB, quad, l15, acc);
#pragma unroll
        for (int mt = 0; mt < 4; mt++)
#pragma unroll
            for (int r = 0; r < 4; r++) {
                int row = WB + mt * 16 + quad * 4 + r;
                float bs = bv[row];
#pragma unroll
                for (int nt = 0; nt < 4; nt++)
                    vbuf[(size_t)(b * CH + row) * SPAT + s0 + nt * 16 + l15] =
                        (__bf16)(acc[mt][nt][r] + bs);
            }
    }
}

// ---- context: ctx[b,h] += p_chunk @ v_chunk^T (unnormalized) ----
__global__ __launch_bounds__(256) void ea_context(const __bf16* pbuf, const __bf16* vbuf, float* ctx) {
    int bi = blockIdx.x, b = bi >> 5, h = (bi >> 4) & 1, chunk = bi & 15;
    int sb = chunk * 1024;
    int t = threadIdx.x, lane = t & 63, wave = t >> 6, quad = lane >> 4, l15 = lane & 15;
    int WB = wave * 32;
    const __bf16* pb = pbuf + (size_t)(b * CH + h * 128) * SPAT;
    const __bf16* vb = vbuf + (size_t)(b * CH + h * 128) * SPAT;
    const f32x4 z = {0.f, 0.f, 0.f, 0.f};
    f32x4 acc[2][8];
#pragma unroll
    for (int mt = 0; mt < 2; mt++)
#pragma unroll
        for (int nt = 0; nt < 8; nt++) acc[mt][nt] = z;

#pragma unroll 2
    for (int ks = 0; ks < 32; ks++) {
        int k0 = sb + ks * 32;
        bf16x8 a[2];
#pragma unroll
        for (int mt = 0; mt < 2; mt++)
            a[mt] = *(const bf16x8*)(pb + (size_t)(WB + mt * 16 + l15) * SPAT + k0 + quad * 8);
        bf16x8 bb[8];
#pragma unroll
        for (int nt = 0; nt < 8; nt++)
            bb[nt] = *(const bf16x8*)(vb + (size_t)(nt * 16 + l15) * SPAT + k0 + quad * 8);
#pragma unroll
        for (int mt = 0; mt < 2; mt++)
#pragma unroll
            for (int nt = 0; nt < 8; nt++)
                acc[mt][nt] = __builtin_amdgcn_mfma_f32_16x16x32_bf16(a[mt], bb[nt], acc[mt][nt], 0, 0, 0);
    }
    float* cbase = ctx + (size_t)(b * 2 + h) * 16384;
#pragma unroll
    for (int mt = 0; mt < 2; mt++)
#pragma unroll
        for (int nt = 0; nt < 8; nt++)
#pragma unroll
            for (int r = 0; r < 4; r++) {
                int kk = WB + mt * 16 + quad * 4 + r, vv = nt * 16 + l15;
                atomicAdd(cbase + kk * 128 + vv, acc[mt][nt][r]);
            }
}

// ---- normalize ctx rows by rowsum, compute pooled mean ----
__global__ void ea_normpool(float* ctx, const float* rowsum, float* pooled) {
    __shared__ float sm[8];
    int bi = blockIdx.x, b = bi >> 1, h = bi & 1;
    float* base = ctx + (size_t)bi * 16384;
    const float* rs = rowsum + b * CH + h * 128;
    float sum = 0.f, dummy = 0.f;
    for (int i = threadIdx.x; i < 16384; i += 256) {
        float v = base[i] / rs[i >> 7];
        base[i] = v;
        sum += v;
    }
    blockReduce2(sum, dummy, sm);
    if (threadIdx.x == 0) pooled[bi] = sum * (1.f / 16384.f);
}

// ---- SE gate + fold w_rep: M[b][o][h*128+kk] = sum_vv w_rep[o][h*128+vv]*ctxc[kk][vv] ----
__global__ __launch_bounds__(256) void ea_M(const float* ctx, const float* pooled,
                                            const float* wfc1, const float* bfc1,
                                            const float* wfc2, const float* bfc2,
                                            const float* wse, const float* bse,
                                            const float* wrep, __bf16* Mbf) {
    __shared__ float L[128 * 128];
    int bi = blockIdx.x, b = bi >> 3, h = (bi >> 2) & 1, strip = bi & 3;
    float p0 = pooled[b * 2], p1 = pooled[b * 2 + 1];
    float z10 = fmaxf(0.f, wfc1[0] * p0 + wfc1[1] * p1 + bfc1[0]);
    float z11 = fmaxf(0.f, wfc1[2] * p0 + wfc1[3] * p1 + bfc1[1]);
    float z20 = wfc2[0] * z10 + wfc2[1] * z11 + bfc2[0];
    float z21 = wfc2[2] * z10 + wfc2[3] * z11 + bfc2[1];
    float g0 = 1.f / (1.f + __expf(-z20)), g1 = 1.f / (1.f + __expf(-z21));
    float a0 = wse[0] * g0, a1 = wse[1] * g1, bs = bse[0];
    const float* c0 = ctx + (size_t)b * 2 * 16384;
    const float* c1 = c0 + 16384;
    for (int i = threadIdx.x; i < 16384; i += 256) L[i] = a0 * c0[i] + a1 * c1[i] + bs;
    __syncthreads();
    int o = strip * 64 + (threadIdx.x & 63), kb = (threadIdx.x >> 6) * 32;
    const float4* wr = (const float4*)(wrep + (size_t)o * 256 + h * 128);
    for (int kk = kb; kk < kb + 32; kk++) {
        const float4* Lr = (const float4*)(L + kk * 128);
        float acc = 0.f;
#pragma unroll 8
        for (int j = 0; j < 32; j++) {
            float4 w4 = wr[j];
            float4 l4 = Lr[j];
            acc += w4.x * l4.x + w4.y * l4.y + w4.z * l4.z + w4.w * l4.w;
        }
        Mbf[(size_t)(b * 256 + o) * 256 + h * 128 + kk] = (__bf16)acc;
    }
}

// ---- final: recompute xn, q = wq@xn+bq, channel-softmax per head, out = M@qsoft + b_rep ----
__global__ __launch_bounds__(256) void ea_final(const float* x, const float* scale, const float* shift,
                                                const __bf16* wqb, const float* bq,
                                                const __bf16* Mbf, const float* brep, float* out) {
    __shared__ __bf16 X[TP * PITCH];
    __shared__ __bf16 Q[TP * PITCH];
    __shared__ float psum[256];
    __shared__ float rcp[TP * 2];
    int bi = blockIdx.x, b = bi >> 8, s0 = (bi & 255) * TP, t = threadIdx.x;
    stage_xn(x + (size_t)b * CH * SPAT + s0, scale, shift, X, t);
    __syncthreads();

    int lane = t & 63, wave = t >> 6, quad = lane >> 4, l15 = lane & 15, WB = wave * 64;
    const f32x4 z = {0.f, 0.f, 0.f, 0.f};

    // matmul1: q-logits -> exp -> Q[px][ch]
    {
        f32x4 acc[4][4];
#pragma unroll
        for (int mt = 0; mt < 4; mt++)
#pragma unroll
            for (int nt = 0; nt < 4; nt++) acc[mt][nt] = z;
        mm256(wqb, X, WB, quad, l15, acc);
#pragma unroll
        for (int mt = 0; mt < 4; mt++)
#pragma unroll
            for (int r = 0; r < 4; r++) {
                int row = WB + mt * 16 + quad * 4 + r;
                float bs = bq[row];
#pragma unroll
                for (int nt = 0; nt < 4; nt++) {
                    float e = __expf(acc[mt][nt][r] + bs);
                    Q[(nt * 16 + l15) * PITCH + row] = (__bf16)e;
                }
            }
    }
    __syncthreads();
    // column sums per (px, head)
    {
        int px = t & 63, hh = (t >> 6) & 1, part = t >> 7;
        const __bf16* qr = Q + px * PITCH + hh * 128 + part * 64;
        float s = 0.f;
#pragma unroll 8
        for (int j = 0; j < 64; j++) s += (float)qr[j];
        psum[t] = s;
    }
    __syncthreads();
    if (t < 128) {
        float tot = psum[t] + psum[t + 128];
        rcp[(t & 63) * 2 + (t >> 6)] = 1.f / tot;
    }
    __syncthreads();
    // normalize Q in place
    for (int e = t; e < TP * 256; e += 256) {
        int px = e >> 8, c = e & 255;
        float v = (float)Q[px * PITCH + c] * rcp[px * 2 + (c >> 7)];
        Q[px * PITCH + c] = (__bf16)v;
    }
    __syncthreads();
    // matmul2: out = M @ qsoft + b_rep
    {
        f32x4 acc[4][4];
#pragma unroll
        for (int mt = 0; mt < 4; mt++)
#pragma unroll
            for (int nt = 0; nt < 4; nt++) acc[mt][nt] = z;
        mm256(Mbf + (size_t)b * 65536, Q, WB, quad, l15, acc);
#pragma unroll
        for (int mt = 0; mt < 4; mt++)
#pragma unroll
            for (int r = 0; r < 4; r++) {
                int row = WB + mt * 16 + quad * 4 + r;
                float bs = brep[row];
#pragma unroll
                for (int nt = 0; nt < 4; nt++)
                    out[(size_t)(b * CH + row) * SPAT + s0 + nt * 16 + l15] = acc[mt][nt][r] + bs;
            }
    }
}

extern "C" void kernel_launch(void* const* d_in, const int* in_sizes, int n_in,
                              void* d_out, int out_size, void* d_ws, size_t ws_size,
                              hipStream_t stream) {
    (void)in_sizes; (void)n_in; (void)out_size; (void)ws_size;
    const float* x     = (const float*)d_in[0];
    const float* gamma = (const float*)d_in[1];
    const float* beta  = (const float*)d_in[2];
    const float* wk    = (const float*)d_in[3];
    const float* bk    = (const float*)d_in[4];
    const float* wq    = (const float*)d_in[5];
    const float* bq    = (const float*)d_in[6];
    const float* wv    = (const float*)d_in[7];
    const float* bv    = (const float*)d_in[8];
    const float* wfc1  = (const float*)d_in[9];
    const float* bfc1  = (const float*)d_in[10];
    const float* wfc2  = (const float*)d_in[11];
    const float* bfc2  = (const float*)d_in[12];
    const float* wse   = (const float*)d_in[13];
    const float* bse   = (const float*)d_in[14];
    const float* wrep  = (const float*)d_in[15];
    const float* brep  = (const float*)d_in[16];

    float* ws = (float*)d_ws;
    __bf16* wkb = (__bf16*)(ws + WS_WKBF);
    __bf16* wqb = (__bf16*)(ws + WS_WQBF);
    __bf16* wvb = (__bf16*)(ws + WS_WVBF);
    __bf16* Mbf = (__bf16*)(ws + WS_MBF);

    // p and v staged as bf16 inside d_out (exactly fills 134 MB); final kernel overwrites with fp32 out
    __bf16* pbuf = (__bf16*)d_out;
    __bf16* vbuf = pbuf + (size_t)BATCH * CH * SPAT;
    float* out = (float*)d_out;

    hipMemsetAsync((void*)(ws + WS_ROWSUM), 0,
                   (size_t)(WS_MBF - WS_ROWSUM) * sizeof(float), stream);
    ea_prep<<<256, 256, 0, stream>>>(wk, wq, wv, wkb, wqb, wvb);
    ea_bnstats<<<256, 256, 0, stream>>>(x, gamma, beta, ws + WS_SCALE, ws + WS_SHIFT);
    ea_projkv<<<2048, 256, 0, stream>>>(x, ws + WS_SCALE, ws + WS_SHIFT, wkb, wvb, bk, bv,
                                        pbuf, vbuf, ws + WS_ROWSUM);
    ea_context<<<256, 256, 0, stream>>>(pbuf, vbuf, ws + WS_CTX);
    ea_normpool<<<16, 256, 0, stream>>>(ws + WS_CTX, ws + WS_ROWSUM, ws + WS_POOLED);
    ea_M<<<64, 256, 0, stream>>>(ws + WS_CTX, ws + WS_POOLED, wfc1, bfc1, wfc2, bfc2,
                                 wse, bse, wrep, Mbf);
    ea_final<<<2048, 256, 0, stream>>>(x, ws + WS_SCALE, ws + WS_SHIFT, wqb, bq, Mbf, brep, out);
}